// Round 9
// baseline (158.993 us; speedup 1.0000x reference)
//
#include <hip/hip_runtime.h>
#include <hip/hip_bf16.h>
#include <cstdint>

typedef __attribute__((ext_vector_type(8))) short bf16x8;
typedef __attribute__((ext_vector_type(4))) float f32x4;
typedef __attribute__((ext_vector_type(4), aligned(4))) float f32x4u;  // 4B-aligned vec load
typedef __attribute__((ext_vector_type(4))) int i32x4;

constexpr int Tt = 12, Nn = 325, DKk = 32;
constexpr int NSLICE = 1536;              // B*H*T
constexpr int SLICE  = Nn * DKk;          // 10400
constexpr int BIASE  = Nn * Nn;           // 105625
constexpr int KSTR = 40;                  // K LDS row stride (shorts): 20-dword bank step -> 2-way (free)
constexpr int VSTR = 360;                 // V^T LDS row stride (shorts); pad cols 326..359 zeroed

__device__ __forceinline__ unsigned short f2bf(float f) {
  union { float f; uint32_t u; } v; v.f = f;
  uint32_t u = v.u;
  uint32_t r = u + 0x7FFFu + ((u >> 16) & 1u);   // RNE
  return (unsigned short)(r >> 16);
}
__device__ __forceinline__ uint32_t pack2(float a, float b) {
  return (uint32_t)f2bf(a) | ((uint32_t)f2bf(b) << 16);
}

__global__ __launch_bounds__(256, 3)
void attn_kernel(const float* __restrict__ Q, const float* __restrict__ K,
                 const float* __restrict__ V, const float* __restrict__ Bias,
                 float* __restrict__ Out)
{
  __shared__ short lds_k[325 * KSTR];        // 26.0 KB
  __shared__ short lds_vt[32 * VSTR];        // 23.0 KB
  // total 49.0 KB -> 3 blocks/CU (12 waves/CU). No P buffer: in-register softmax.

  // XCD-grouped remap: 12 t-slices of one (b,h) on one XCD -> bias L2-resident
  const int bid = blockIdx.x;
  const int x = bid & 7, u = bid >> 3;
  const int s = (((u / Tt) << 3) + x) * Tt + (u % Tt);

  const int bh = s / Tt;
  const size_t base  = (size_t)s * SLICE;
  const size_t bbase = (size_t)bh * BIASE;
  const int tid = threadIdx.x;

  // ---- stage K as bf16 ----
  for (int i = tid; i < SLICE / 2; i += 256) {
    const int e0 = i << 1;
    const int row = e0 >> 5, col = e0 & 31;
    const float2 f = *(const float2*)(K + base + e0);
    *(uint32_t*)&lds_k[row * KSTR + col] = pack2(f.x, f.y);
  }
  // ---- stage V^T as bf16 ----
  for (int i = tid; i < 32 * 163; i += 256) {
    const int d = i & 31, jp = i >> 5;
    const int j0 = jp << 1;
    const float a  = V[base + (size_t)j0 * DKk + d];
    const float b2 = (j0 + 1 < Nn) ? V[base + (size_t)(j0 + 1) * DKk + d] : 0.f;
    *(uint32_t*)&lds_vt[d * VSTR + j0] = pack2(a, b2);
  }
  // ---- zero V^T pad cols 326..359 (kb=10 reads reach col 351) ----
  for (int i = tid; i < 32 * 34; i += 256) {
    const int d = i / 34, c = 326 + (i - d * 34);
    lds_vt[d * VSTR + c] = 0;
  }
  __syncthreads();

  // 256 threads = FOUR wave64s
  const int wave = tid >> 6, lane = tid & 63;
  const int r16 = lane & 15, grp = lane >> 4;
  const int grp8 = grp << 3, grp4 = grp << 2;
  const bool upper = lane >= 32;                  // dest grp>=2 -> needs jt1 tile
  const int srcp0 = ((grp & 1) << 5) + r16;       // src lane for A-frag e0..3
  const int srcp1 = srcp0 + 16;                   // src lane for A-frag e4..7
  const float scale = 0.17677669529663687f;       // 1/sqrt(32), folded into Q
  const float* __restrict__ bb = Bias + bbase;

  auto process = [&](const int qtA, const int qtB) {
    const int qb[2] = { qtA << 4, qtB << 4 };

    // Q fragments (B-operand layout for swapped QK: col=q=r16, k=grp*8+e)
    bf16x8 aq[2];
    int rowoff[2];                                 // clamped bias-row offset for q=qb+r16
    #pragma unroll
    for (int t = 0; t < 2; ++t) {
      int r = qb[t] + r16; r = r < Nn ? r : (Nn - 1);
      rowoff[t] = r * Nn;
      const float* p = Q + base + (size_t)r * DKk + grp8;
      const float4 a0 = *(const float4*)p, a1 = *(const float4*)(p + 4);
      aq[t][0] = (short)f2bf(a0.x * scale); aq[t][1] = (short)f2bf(a0.y * scale);
      aq[t][2] = (short)f2bf(a0.z * scale); aq[t][3] = (short)f2bf(a0.w * scale);
      aq[t][4] = (short)f2bf(a1.x * scale); aq[t][5] = (short)f2bf(a1.y * scale);
      aq[t][6] = (short)f2bf(a1.z * scale); aq[t][7] = (short)f2bf(a1.w * scale);
    }

    f32x4 acc0[2] = { (f32x4)(0.f), (f32x4)(0.f) };
    f32x4 acc1[2] = { (f32x4)(0.f), (f32x4)(0.f) };
    float rsl[2] = { 0.f, 0.f };                   // per-lane partial denom (q=r16)

    // ---- kb = 0..9: keys 0..319, completely mask/clamp-free ----
    #pragma unroll
    for (int kb = 0; kb < 10; ++kb) {
      const int j0 = kb << 5, j1 = j0 + 16;
      const bf16x8 bk0 = *(const bf16x8*)&lds_k[(j0 + r16) * KSTR + grp8];
      const bf16x8 bk1 = *(const bf16x8*)&lds_k[(j1 + r16) * KSTR + grp8];
      const bf16x8 bv0 = *(const bf16x8*)&lds_vt[r16 * VSTR + j0 + grp8];
      const bf16x8 bv1 = *(const bf16x8*)&lds_vt[(16 + r16) * VSTR + j0 + grp8];

      #pragma unroll
      for (int t = 0; t < 2; ++t) {
        // bias: contiguous per-lane float4 (row q=r16, keys j+grp*4..+3), 4B-aligned
        const f32x4u b0 = *(const f32x4u*)&bb[rowoff[t] + j0 + grp4];
        const f32x4u b1 = *(const f32x4u*)&bb[rowoff[t] + j1 + grp4];
        // S^T tiles: row=key, col=q
        const f32x4 st0 = __builtin_amdgcn_mfma_f32_16x16x32_bf16(bk0, aq[t], (f32x4)(0.f), 0, 0, 0);
        const f32x4 st1 = __builtin_amdgcn_mfma_f32_16x16x32_bf16(bk1, aq[t], (f32x4)(0.f), 0, 0, 0);
        float p0[4], p1[4];
        #pragma unroll
        for (int m = 0; m < 4; ++m) {
          p0[m] = __expf(st0[m] + b0[m]);
          p1[m] = __expf(st1[m] + b1[m]);
          rsl[t] += p0[m] + p1[m];
        }
        const int pk01_0 = (int)pack2(p0[0], p0[1]);
        const int pk23_0 = (int)pack2(p0[2], p0[3]);
        const int pk01_1 = (int)pack2(p1[0], p1[1]);
        const int pk23_1 = (int)pack2(p1[2], p1[3]);
        // Redistribute S^T -> PV A-frag (P[q=r16][key=grp*8+e]).
        // ALL shuffles full-wave & unconditional (operands computed by every lane);
        // divergent selection only AFTER, on defined values. (Round-8 bug: divergent
        // ?: around __shfl let the compiler sink pk*_1/exp into a masked region.)
        const int a0 = __shfl(pk01_0, srcp0, 64);
        const int a1 = __shfl(pk23_0, srcp0, 64);
        const int a2 = __shfl(pk01_0, srcp1, 64);
        const int a3 = __shfl(pk23_0, srcp1, 64);
        const int b0s = __shfl(pk01_1, srcp0, 64);
        const int b1s = __shfl(pk23_1, srcp0, 64);
        const int b2s = __shfl(pk01_1, srcp1, 64);
        const int b3s = __shfl(pk23_1, srcp1, 64);
        union { i32x4 i; bf16x8 h; } uap;
        uap.i[0] = upper ? b0s : a0;
        uap.i[1] = upper ? b1s : a1;
        uap.i[2] = upper ? b2s : a2;
        uap.i[3] = upper ? b3s : a3;
        acc0[t] = __builtin_amdgcn_mfma_f32_16x16x32_bf16(uap.h, bv0, acc0[t], 0, 0, 0);
        acc1[t] = __builtin_amdgcn_mfma_f32_16x16x32_bf16(uap.h, bv1, acc1[t], 0, 0, 0);
      }
    }

    // ---- kb = 10 tail: keys 320..351 (valid 320..324), masked/clamped ----
    {
      int kr = 320 + r16; kr = kr < Nn ? kr : (Nn - 1);
      const bf16x8 bk0 = *(const bf16x8*)&lds_k[kr * KSTR + grp8];
      const bf16x8 bv0 = *(const bf16x8*)&lds_vt[r16 * VSTR + 320 + grp8];
      const bf16x8 bv1 = *(const bf16x8*)&lds_vt[(16 + r16) * VSTR + 320 + grp8];
      #pragma unroll
      for (int t = 0; t < 2; ++t) {
        const f32x4 st0 = __builtin_amdgcn_mfma_f32_16x16x32_bf16(bk0, aq[t], (f32x4)(0.f), 0, 0, 0);
        float p0[4];
        #pragma unroll
        for (int m = 0; m < 4; ++m) {
          const int key = 320 + grp4 + m;
          const int keyc = key < Nn ? key : (Nn - 1);
          float xv = st0[m] + bb[rowoff[t] + keyc];   // scalar clamped bias load
          xv = key < Nn ? xv : -1e30f;                // mask pad keys -> p=0
          p0[m] = __expf(xv);
          rsl[t] += p0[m];
        }
        const int pk01_0 = (int)pack2(p0[0], p0[1]);
        const int pk23_0 = (int)pack2(p0[2], p0[3]);
        const int a0 = __shfl(pk01_0, srcp0, 64);
        const int a1 = __shfl(pk23_0, srcp0, 64);
        const int a2 = __shfl(pk01_0, srcp1, 64);
        const int a3 = __shfl(pk23_0, srcp1, 64);
        union { i32x4 i; bf16x8 h; } uap;
        uap.i[0] = upper ? 0 : a0;     // keys 336..351 -> P=0
        uap.i[1] = upper ? 0 : a1;
        uap.i[2] = upper ? 0 : a2;
        uap.i[3] = upper ? 0 : a3;
        acc0[t] = __builtin_amdgcn_mfma_f32_16x16x32_bf16(uap.h, bv0, acc0[t], 0, 0, 0);
        acc1[t] = __builtin_amdgcn_mfma_f32_16x16x32_bf16(uap.h, bv1, acc1[t], 0, 0, 0);
      }
    }

    // ---- epilogue: denom reduce (across grp lanes) + normalize + store ----
    #pragma unroll
    for (int t = 0; t < 2; ++t) {
      float r = rsl[t];
      r += __shfl_xor(r, 16);
      r += __shfl_xor(r, 32);                       // denom for q=qb+r16, replicated
      #pragma unroll
      for (int m = 0; m < 4; ++m) {
        const float rm = __shfl(r, grp4 + m, 64);   // denom for q=qb+grp*4+m
        const int row = qb[t] + grp4 + m;
        if (row < Nn) {
          const float inv = 1.f / rm;
          Out[base + (size_t)row * DKk + r16]      = acc0[t][m] * inv;
          Out[base + (size_t)row * DKk + 16 + r16] = acc1[t][m] * inv;
        }
      }
    }
  };

  // Exact coverage (wave in 0..3): pairs (w,w+4),(w+8,w+12),(w+16,20).
  // Tiles 0..19 each once; tile 20 by waves 0..3 with identical stores (benign).
  process(wave, wave + 4);
  process(wave + 8, wave + 12);
  process(wave + 16, 20);
}

extern "C" void kernel_launch(void* const* d_in, const int* in_sizes, int n_in,
                              void* d_out, int out_size, void* d_ws, size_t ws_size,
                              hipStream_t stream) {
  const float* Q    = (const float*)d_in[0];
  const float* K    = (const float*)d_in[1];
  const float* V    = (const float*)d_in[2];
  const float* Bias = (const float*)d_in[3];
  float* Out = (float*)d_out;
  attn_kernel<<<dim3(NSLICE), dim3(256), 0, stream>>>(Q, K, V, Bias, Out);
}